// Round 1
// baseline (415.573 us; speedup 1.0000x reference)
//
#include <hip/hip_runtime.h>
#include <stdint.h>

// B=128, S=1024, LAST=258, FEAT=255, HIDDEN=1024 — all f32 in/out.
#define NBATCH 128
#define SEQ    1024
#define ROWE   258
#define NPART  16

// ws layout (bytes), total ~3.42 MB
#define WS_KQP   0                       // float kqp[4][128][256]     512 KB
#define WS_PART  524288                  // float part[128][16][260]  2.03 MB
#define WS_WF    2654208                 // float wf[128][256]         128 KB
#define WS_REST  2785280                 // float resT[1024][128]      512 KB
#define WS_H1P   3309568                 // float h1pre[128][512]      256 KB
#define WS_CNT   3571712                 // int   cnt[128]             512 B

static __device__ __forceinline__ float fexp2(float x){ return __builtin_amdgcn_exp2f(x); }

// ---------------------------------------------------------------------------
// qk: grid (64 batch-pairs, 4 h-quarters). kqp[hh][b][f] = partial over h-quarter
//     of (qb[h] + sum_j archi[b][j] qW[h][j]) * kW[h][f]. Unscaled; attn sums the
//     4 partials and applies log2(e)/sqrt(258). Also zero-inits h1pre, d_out and
//     the attn merge counters (all consumed via atomicAdd later; re-armed every
//     graph replay before attn in stream order).
//     q.kb term dropped: constant per-batch score shift, softmax-invariant.
__global__ __launch_bounds__(256) void qk_kernel(const float* __restrict__ in,
    const float* __restrict__ kW, const float* __restrict__ qW,
    const float* __restrict__ qb, float* __restrict__ kqp,
    float* __restrict__ h1pre, float* __restrict__ out, int* __restrict__ cnt)
{
    __shared__ float qv[2][256];
    const int bb = blockIdx.x;         // 0..63
    const int hh = blockIdx.y;         // 0..3
    const int t  = threadIdx.x;
    const int b0 = bb * 2;
    if (hh == 0) {
        h1pre[(size_t)b0 * 512 + t]             = 0.f;
        h1pre[(size_t)b0 * 512 + 256 + t]       = 0.f;
        h1pre[(size_t)(b0 + 1) * 512 + t]       = 0.f;
        h1pre[(size_t)(b0 + 1) * 512 + 256 + t] = 0.f;
        if (t < 4) out[b0 * 2 + t] = 0.f;
        if (t < 2) cnt[b0 + t] = 0;
    }
    const int h = hh * 256 + t;
    const float w0 = qW[h * 3 + 0], w1 = qW[h * 3 + 1], w2 = qW[h * 3 + 2], bq = qb[h];
    #pragma unroll
    for (int u = 0; u < 2; u++) {
        const size_t abase = (size_t)(b0 + u) * (SEQ * ROWE) + 255; // input[b,0,255..257]
        qv[u][t] = bq + in[abase] * w0 + in[abase + 1] * w1 + in[abase + 2] * w2;
    }
    __syncthreads();
    const int col = (t < 255) ? t : 254;            // t==255 is a pad slot
    const float* kWp = kW + (size_t)(hh * 256) * 255 + col;
    float acc0 = 0.f, acc1 = 0.f;
    #pragma unroll 16
    for (int i = 0; i < 256; i++) {
        const float kv = kWp[(size_t)i * 255];      // coalesced across t
        acc0 = fmaf(qv[0][i], kv, acc0);            // LDS broadcast reads
        acc1 = fmaf(qv[1][i], kv, acc1);
    }
    kqp[(size_t)((hh << 7) + b0) * 256 + t]       = (t < 255) ? acc0 : 0.f;
    kqp[(size_t)((hh << 7) + b0 + 1) * 256 + t]   = (t < 255) ? acc1 : 0.f;
}

// ---------------------------------------------------------------------------
// attn: grid (16,128) — (S-chunk of 64 rows, batch). Wave per row, lane i
// covers f={2i,2i+1,128+2i,128+2i+1}; butterfly dot, exp2-domain online
// softmax, weighted-feature accumulator in registers. One streaming input read.
// Fused comb: the 16th block to finish a batch (device-scope counter) merges
// the 16 partials into wf[b][:]. Release = syncthreads (vmcnt drain) +
// threadfence (L2 writeback, cross-XCD); acquire = threadfence (L1/L2 inv —
// also kills stale lines cached from the previous graph replay).
__global__ __launch_bounds__(256) void attn_kernel(const float* __restrict__ in,
                                                   const float* __restrict__ kqp,
                                                   float* __restrict__ part,
                                                   float* __restrict__ wf,
                                                   int* __restrict__ cnt)
{
    __shared__ float sm[4], sl[4], sacc[4][256];
    __shared__ int lastf;
    const int p = blockIdx.x, b = blockIdx.y;
    const int t = threadIdx.x, w = t >> 6, lane = t & 63;

    float2 k0 = make_float2(0.f, 0.f), k1 = make_float2(0.f, 0.f);
    #pragma unroll
    for (int hh = 0; hh < 4; hh++) {
        const float* pp = kqp + (size_t)((hh << 7) + b) * 256;
        const float2 u = *(const float2*)(pp + 2 * lane);
        const float2 v = *(const float2*)(pp + 128 + 2 * lane);
        k0.x += u.x; k0.y += u.y; k1.x += v.x; k1.y += v.y;
    }
    const float SCALE = (float)(1.4426950408889634 / 16.062378404209142); // log2(e)/sqrt(258)
    k0.x *= SCALE; k0.y *= SCALE; k1.x *= SCALE; k1.y *= SCALE;

    // rows s = p*64 + w + 4*i. Row base byte offset = s*1032 (8-aligned) -> float2 ok.
    const float* rp = in + ((size_t)b * SEQ + p * 64 + w) * ROWE;
    float m = -INFINITY, l = 0.f;
    float a0 = 0.f, a1 = 0.f, a2 = 0.f, a3 = 0.f;

    float2 x = *(const float2*)(rp + 2 * lane);
    float2 y = *(const float2*)(rp + 128 + 2 * lane);
    #pragma unroll
    for (int i = 0; i < 16; i++) {
        const float e0 = x.x, e1 = x.y, e2 = y.x, e3 = y.y;
        if (i < 15) {                      // prefetch row s+4
            rp += 4 * ROWE;
            x = *(const float2*)(rp + 2 * lane);
            y = *(const float2*)(rp + 128 + 2 * lane);
        }
        float d = fmaf(e0, k0.x, fmaf(e1, k0.y, fmaf(e2, k1.x, e3 * k1.y)));
        #pragma unroll
        for (int off = 32; off > 0; off >>= 1) d += __shfl_xor(d, off, 64);
        const float mn = fmaxf(m, d);
        const float cc = fexp2(m - mn);    // first iter: exp2(-inf)=0
        const float wt = fexp2(d - mn);
        l  = fmaf(l, cc, wt);
        a0 = fmaf(a0, cc, wt * e0);
        a1 = fmaf(a1, cc, wt * e1);
        a2 = fmaf(a2, cc, wt * e2);
        a3 = fmaf(a3, cc, wt * e3);
        m = mn;
    }

    ((float2*)(sacc[w]))[lane]       = make_float2(a0, a1);
    ((float2*)(sacc[w] + 128))[lane] = make_float2(a2, a3);
    if (lane == 0) { sm[w] = m; sl[w] = l; }
    __syncthreads();

    const float M  = fmaxf(fmaxf(sm[0], sm[1]), fmaxf(sm[2], sm[3]));
    const float c0 = fexp2(sm[0] - M), c1 = fexp2(sm[1] - M);
    const float c2 = fexp2(sm[2] - M), c3 = fexp2(sm[3] - M);
    const float acc = c0 * sacc[0][t] + c1 * sacc[1][t] + c2 * sacc[2][t] + c3 * sacc[3][t];
    float* o = part + ((size_t)b * NPART + p) * 260;
    o[t] = acc;
    if (t == 0) {
        o[256] = M;
        o[257] = c0 * sl[0] + c1 * sl[1] + c2 * sl[2] + c3 * sl[3];
    }

    // ---- fused comb: last block per batch merges the 16 partials ----
    __syncthreads();                        // all o[] stores issued + drained (vmcnt0 before barrier)
    if (t == 0) {
        __threadfence();                    // release: write back past L2 (cross-XCD)
        lastf = (atomicAdd(&cnt[b], 1) == NPART - 1);
    }
    __syncthreads();
    if (!lastf) return;
    __threadfence();                        // acquire: invalidate before reading peers' partials
    const float* pb = part + (size_t)b * NPART * 260;
    float Mv = -INFINITY;
    #pragma unroll
    for (int q = 0; q < NPART; q++) Mv = fmaxf(Mv, pb[q * 260 + 256]);
    float L = 0.f, a = 0.f;
    #pragma unroll
    for (int q = 0; q < NPART; q++) {
        const float cc = fexp2(pb[q * 260 + 256] - Mv);
        L = fmaf(cc, pb[q * 260 + 257], L);
        a = fmaf(cc, pb[q * 260 + t], a);
    }
    wf[b * 256 + t] = (t < 255) ? a / L : 0.f;
}

// ---------------------------------------------------------------------------
// res: resT[h][b] = vb[h] + sum_f wf[b][f]*vW[h][f]. 128 blocks, each an
// 8-row h-slice for all 128 batches; wf chunked through LDS [f][b].
__global__ __launch_bounds__(512) void res_kernel(const float* __restrict__ vW,
                                                  const float* __restrict__ vb,
                                                  const float* __restrict__ wf,
                                                  float* __restrict__ resT)
{
    __shared__ float vws[8][256];    // 8 KB
    __shared__ float wfs[64][130];   // 33.3 KB (pad 130: read banks (2f+b)&31 -> free)
    const int g = blockIdx.x, t = threadIdx.x;
    #pragma unroll
    for (int i = 0; i < 4; i++) {
        const int idx = i * 512 + t, f = idx & 255, hh = idx >> 8;
        vws[hh][f] = (f < 255) ? vW[(g * 8 + hh) * 255 + f] : 0.f;
    }
    const int b = t & 127, ho = t >> 7;      // ho wave-uniform (w>>1)
    const int fl = t & 63, wv = t >> 6;
    float acc0 = 0.f, acc1 = 0.f;
    for (int c = 0; c < 4; c++) {
        __syncthreads();
        #pragma unroll
        for (int i = 0; i < 16; i++) {
            const int bb = i * 8 + wv;
            wfs[fl][bb] = wf[bb * 256 + c * 64 + fl];   // coalesced global read
        }
        __syncthreads();
        #pragma unroll 8
        for (int f = 0; f < 64; f++) {
            const float w2 = wfs[f][b];
            acc0 = fmaf(w2, vws[ho][c * 64 + f], acc0);
            acc1 = fmaf(w2, vws[ho + 4][c * 64 + f], acc1);
        }
    }
    const int h0 = g * 8 + ho, h1 = h0 + 4;
    resT[h0 * 128 + b] = acc0 + vb[h0];
    resT[h1 * 128 + b] = acc1 + vb[h1];
}

// ---------------------------------------------------------------------------
// h1: h1pre[b][j] += sum_{h in kchunk} resT[h][b]*W1[j][h].
// Grid (32 jblk, 2 bhalf, 4 kchunk); K-split partials via f32 atomicAdd.
__global__ __launch_bounds__(256) void h1_kernel(const float* __restrict__ W1,
                                                 const float* __restrict__ resT,
                                                 float* __restrict__ h1pre)
{
    __shared__ float W1s[16][256];   // 16 KB
    __shared__ float ress[64][66];   // 16.9 KB
    const int j0 = blockIdx.x * 16, b0 = blockIdx.y * 64, h0 = blockIdx.z * 256;
    const int t = threadIdx.x;
    #pragma unroll
    for (int i = 0; i < 16; i++) {
        const int idx = i * 256 + t, hl = idx & 255, jj = idx >> 8;
        W1s[jj][hl] = W1[(j0 + jj) * 1024 + h0 + hl];
    }
    const int bb = t & 63, jg = t >> 6;      // jg wave-uniform
    float acc[4] = {0.f, 0.f, 0.f, 0.f};
    for (int sc = 0; sc < 4; sc++) {
        __syncthreads();
        {
            const int bl = t & 63, wvv = t >> 6;
            #pragma unroll
            for (int i = 0; i < 16; i++) {
                const int hl = i * 4 + wvv;
                ress[hl][bl] = resT[(h0 + sc * 64 + hl) * 128 + b0 + bl];
            }
        }
        __syncthreads();
        #pragma unroll 4
        for (int hl = 0; hl < 64; hl++) {
            const float rv = ress[hl][bb];
            acc[0] = fmaf(rv, W1s[jg * 4 + 0][sc * 64 + hl], acc[0]);
            acc[1] = fmaf(rv, W1s[jg * 4 + 1][sc * 64 + hl], acc[1]);
            acc[2] = fmaf(rv, W1s[jg * 4 + 2][sc * 64 + hl], acc[2]);
            acc[3] = fmaf(rv, W1s[jg * 4 + 3][sc * 64 + hl], acc[3]);
        }
    }
    #pragma unroll
    for (int k = 0; k < 4; k++)
        atomicAdd(&h1pre[(size_t)(b0 + bb) * 512 + j0 + jg * 4 + k], acc[k]);
}

// ---------------------------------------------------------------------------
// h2out: h2[b][j2] = relu(b2[j2] + sum_j W2[j2][j]*relu(h1pre[b][j]+b1[j]));
// then partial out[b][o] += sum_{j2 in block} h2 * W3[o][j2] via atomicAdd
// (d_out zero-initialized by qk_kernel). Grid (32 j2blk, 2 bhalf).
__global__ __launch_bounds__(256) void h2out_kernel(const float* __restrict__ W2,
    const float* __restrict__ b1, const float* __restrict__ b2,
    const float* __restrict__ W3, const float* __restrict__ b3,
    const float* __restrict__ h1pre, float* __restrict__ out)
{
    __shared__ float W2s[8][512];    // 16 KB
    __shared__ float h1s[64][66];    // 16.9 KB
    __shared__ float po[4][64][2];   // 2 KB
    const int j20 = blockIdx.x * 8, b0 = blockIdx.y * 64;
    const int t = threadIdx.x;
    #pragma unroll
    for (int i = 0; i < 16; i++) {
        const int idx = i * 256 + t, jl = idx & 511, jj = idx >> 9;
        W2s[jj][jl] = W2[(j20 + jj) * 512 + jl];
    }
    const int bb = t & 63, jg = t >> 6;
    float acc[2] = {0.f, 0.f};
    for (int sc = 0; sc < 8; sc++) {
        __syncthreads();
        {
            const int jl = t & 63, wvv = t >> 6;
            #pragma unroll
            for (int i = 0; i < 16; i++) {
                const int bl = i * 4 + wvv;
                const float v = h1pre[(size_t)(b0 + bl) * 512 + sc * 64 + jl] + b1[sc * 64 + jl];
                h1s[jl][bl] = fmaxf(v, 0.f);   // relu applied on load
            }
        }
        __syncthreads();
        #pragma unroll 4
        for (int jl = 0; jl < 64; jl++) {
            const float hv = h1s[jl][bb];
            acc[0] = fmaf(hv, W2s[jg * 2 + 0][sc * 64 + jl], acc[0]);
            acc[1] = fmaf(hv, W2s[jg * 2 + 1][sc * 64 + jl], acc[1]);
        }
    }
    float p0 = 0.f, p1 = 0.f;
    #pragma unroll
    for (int k = 0; k < 2; k++) {
        const int j2 = j20 + jg * 2 + k;
        const float h2v = fmaxf(acc[k] + b2[j2], 0.f);
        p0 = fmaf(h2v, W3[j2],       p0);
        p1 = fmaf(h2v, W3[256 + j2], p1);
    }
    po[jg][bb][0] = p0;
    po[jg][bb][1] = p1;
    __syncthreads();
    if (t < 128) {
        const int b = t & 63, o = t >> 6;
        float s = po[0][b][o] + po[1][b][o] + po[2][b][o] + po[3][b][o];
        if (blockIdx.x == 0) s += b3[o];     // add bias exactly once per (b,o)
        atomicAdd(&out[(b0 + b) * 2 + o], s);
    }
}

// ---------------------------------------------------------------------------
extern "C" void kernel_launch(void* const* d_in, const int* in_sizes, int n_in,
                              void* d_out, int out_size, void* d_ws, size_t ws_size,
                              hipStream_t stream)
{
    (void)in_sizes; (void)n_in; (void)out_size; (void)ws_size;
    const float* in = (const float*)d_in[0];
    const float* kW = (const float*)d_in[1];
    // d_in[2] = kb: unused — q.kb is a per-batch constant score shift (softmax-invariant)
    const float* vW = (const float*)d_in[3];
    const float* vb = (const float*)d_in[4];
    const float* qW = (const float*)d_in[5];
    const float* qb = (const float*)d_in[6];
    const float* W1 = (const float*)d_in[7];
    const float* b1 = (const float*)d_in[8];
    const float* W2 = (const float*)d_in[9];
    const float* b2 = (const float*)d_in[10];
    const float* W3 = (const float*)d_in[11];
    const float* b3 = (const float*)d_in[12];

    char* ws = (char*)d_ws;
    float* kqp   = (float*)(ws + WS_KQP);
    float* part  = (float*)(ws + WS_PART);
    float* wf    = (float*)(ws + WS_WF);
    float* resT  = (float*)(ws + WS_REST);
    float* h1pre = (float*)(ws + WS_H1P);
    int*   cnt   = (int*)  (ws + WS_CNT);

    qk_kernel   <<<dim3(64, 4),         256, 0, stream>>>(in, kW, qW, qb, kqp, h1pre, (float*)d_out, cnt);
    attn_kernel <<<dim3(NPART, NBATCH), 256, 0, stream>>>(in, kqp, part, wf, cnt);
    res_kernel  <<<128,                 512, 0, stream>>>(vW, vb, wf, resT);
    h1_kernel   <<<dim3(32, 2, 4),      256, 0, stream>>>(W1, resT, h1pre);
    h2out_kernel<<<dim3(32, 2),         256, 0, stream>>>(W2, b1, b2, W3, b3, h1pre, (float*)d_out);
}

// Round 2
// 322.115 us; speedup vs baseline: 1.2901x; 1.2901x over previous
//
#include <hip/hip_runtime.h>
#include <stdint.h>

// B=128, S=1024, LAST=258, FEAT=255, HIDDEN=1024 — all f32 in/out.
#define NBATCH 128
#define SEQ    1024
#define ROWE   258
#define NPART  16

// ws layout (bytes), total ~3.41 MB
#define WS_KQP   0                       // float kqp[4][128][256]     512 KB
#define WS_PART  524288                  // float part[128][16][260]  2.03 MB
#define WS_WF    2654208                 // float wf[128][256]         128 KB
#define WS_REST  2785280                 // float resT[1024][128]      512 KB
#define WS_H1P   3309568                 // float h1pre[128][512]      256 KB

// NOTE (R1 post-mortem): fusing comb into attn via device-scope threadfence +
// atomic counter made attn 235 µs (was <79): on gfx950 __threadfence is an L2
// writeback/invalidate (per-XCD L2s non-coherent) — 2048 release fences
// serialized at L2 and evicted the streamed input. Never cross-block-fuse with
// fences here; the inter-kernel barrier is far cheaper.

static __device__ __forceinline__ float fexp2(float x){ return __builtin_amdgcn_exp2f(x); }

// ---------------------------------------------------------------------------
// qk: grid (64 batch-pairs, 4 h-quarters). kqp[hh][b][f] = partial over h-quarter
//     of (qb[h] + sum_j archi[b][j] qW[h][j]) * kW[h][f]. Unscaled; attn sums the
//     4 partials and applies log2(e)/sqrt(258). Also zero-inits h1pre and d_out
//     (consumed via atomicAdd later). q.kb dropped: softmax-invariant shift.
__global__ __launch_bounds__(256) void qk_kernel(const float* __restrict__ in,
    const float* __restrict__ kW, const float* __restrict__ qW,
    const float* __restrict__ qb, float* __restrict__ kqp,
    float* __restrict__ h1pre, float* __restrict__ out)
{
    __shared__ float qv[2][256];
    const int bb = blockIdx.x;         // 0..63
    const int hh = blockIdx.y;         // 0..3
    const int t  = threadIdx.x;
    const int b0 = bb * 2;
    if (hh == 0) {
        h1pre[(size_t)b0 * 512 + t]             = 0.f;
        h1pre[(size_t)b0 * 512 + 256 + t]       = 0.f;
        h1pre[(size_t)(b0 + 1) * 512 + t]       = 0.f;
        h1pre[(size_t)(b0 + 1) * 512 + 256 + t] = 0.f;
        if (t < 4) out[b0 * 2 + t] = 0.f;
    }
    const int h = hh * 256 + t;
    const float w0 = qW[h * 3 + 0], w1 = qW[h * 3 + 1], w2 = qW[h * 3 + 2], bq = qb[h];
    #pragma unroll
    for (int u = 0; u < 2; u++) {
        const size_t abase = (size_t)(b0 + u) * (SEQ * ROWE) + 255; // input[b,0,255..257]
        qv[u][t] = bq + in[abase] * w0 + in[abase + 1] * w1 + in[abase + 2] * w2;
    }
    __syncthreads();
    const int col = (t < 255) ? t : 254;            // t==255 is a pad slot
    const float* kWp = kW + (size_t)(hh * 256) * 255 + col;
    float acc0 = 0.f, acc1 = 0.f;
    #pragma unroll 16
    for (int i = 0; i < 256; i++) {
        const float kv = kWp[(size_t)i * 255];      // coalesced across t
        acc0 = fmaf(qv[0][i], kv, acc0);            // LDS broadcast reads
        acc1 = fmaf(qv[1][i], kv, acc1);
    }
    kqp[(size_t)((hh << 7) + b0) * 256 + t]       = (t < 255) ? acc0 : 0.f;
    kqp[(size_t)((hh << 7) + b0 + 1) * 256 + t]   = (t < 255) ? acc1 : 0.f;
}

// ---------------------------------------------------------------------------
// attn: grid (16,128) — (S-chunk of 64 rows, batch). NEW geometry: 32 lanes per
// row, 2 rows per wave concurrently (lane half hf owns row p*64+w*16+2i+hf,
// 8 floats per lane). Butterfly is 5 steps over 32 lanes, 8 iters/wave
// (40 shuffles vs 96 before); softmax-update serial issues halved; per-wave
// reads are 2 adjacent rows (contiguous 2 KB span). 8 online states (4 waves ×
// 2 halves) merged through LDS at the end. One streaming input read.
__global__ __launch_bounds__(256, 8) void attn_kernel(const float* __restrict__ in,
                                                      const float* __restrict__ kqp,
                                                      float* __restrict__ part)
{
    __shared__ float sM[8], sL[8], sacc[8][256];
    const int p = blockIdx.x, b = blockIdx.y;
    const int t = threadIdx.x, w = t >> 6, lane = t & 63;
    const int hf = lane >> 5, sub = lane & 31;   // half (row parity), sub-lane

    const float SCALE = (float)(1.4426950408889634 / 16.062378404209142); // log2(e)/sqrt(258)
    // k registers: lane covers features f = sub*8 + j. kqp rows 1 KB-aligned ->
    // sub*32 B offsets are 16 B-aligned: float4 loads OK. f=255 slot is 0 (qk pad).
    float k[8];
    {
        float s0x=0.f,s0y=0.f,s0z=0.f,s0w=0.f, s1x=0.f,s1y=0.f,s1z=0.f,s1w=0.f;
        #pragma unroll
        for (int hh = 0; hh < 4; hh++) {
            const float4* pp = (const float4*)(kqp + (size_t)((hh << 7) + b) * 256 + sub * 8);
            const float4 u = pp[0], v = pp[1];
            s0x+=u.x; s0y+=u.y; s0z+=u.z; s0w+=u.w;
            s1x+=v.x; s1y+=v.y; s1z+=v.z; s1w+=v.w;
        }
        k[0]=s0x*SCALE; k[1]=s0y*SCALE; k[2]=s0z*SCALE; k[3]=s0w*SCALE;
        k[4]=s1x*SCALE; k[5]=s1y*SCALE; k[6]=s1z*SCALE; k[7]=s1w*SCALE;
    }

    // rows r = p*64 + w*16 + 2*i + hf, i=0..7. Row byte base = r*1032 (8-aligned);
    // per-lane 8 floats at +sub*32 B -> float2 loads aligned.
    const float* rp = in + ((size_t)b * SEQ + p * 64 + w * 16 + hf) * ROWE + sub * 8;

    float x[8], xn[8], a[8];
    #pragma unroll
    for (int j = 0; j < 8; j++) a[j] = 0.f;
    #pragma unroll
    for (int j = 0; j < 8; j += 2) {
        const float2 v2 = *(const float2*)(rp + j);
        x[j] = v2.x; x[j+1] = v2.y;
    }
    rp += 2 * ROWE;
    float m = -INFINITY, l = 0.f;

    #pragma unroll
    for (int i = 0; i < 8; i++) {
        if (i < 7) {                       // prefetch next row pair
            #pragma unroll
            for (int j = 0; j < 8; j += 2) {
                const float2 v2 = *(const float2*)(rp + j);
                xn[j] = v2.x; xn[j+1] = v2.y;
            }
            rp += 2 * ROWE;
        }
        // tree dot: shorter dependent chain than a linear fma chain
        const float d0 = fmaf(x[0], k[0], x[1] * k[1]);
        const float d1 = fmaf(x[2], k[2], x[3] * k[3]);
        const float d2 = fmaf(x[4], k[4], x[5] * k[5]);
        const float d3 = fmaf(x[6], k[6], x[7] * k[7]);
        float d = (d0 + d1) + (d2 + d3);
        #pragma unroll
        for (int off = 16; off > 0; off >>= 1) d += __shfl_xor(d, off, 64); // stays in half
        const float mn = fmaxf(m, d);
        const float cc = fexp2(m - mn);    // first iter: exp2(-inf)=0
        const float wt = fexp2(d - mn);
        l = fmaf(l, cc, wt);
        #pragma unroll
        for (int j = 0; j < 8; j++) a[j] = fmaf(a[j], cc, wt * x[j]);
        m = mn;
        if (i < 7) {
            #pragma unroll
            for (int j = 0; j < 8; j++) x[j] = xn[j];   // register rename, free
        }
    }

    const int id = w * 2 + hf;             // 8 partial states per block
    #pragma unroll
    for (int j = 0; j < 8; j += 2)
        *(float2*)(&sacc[id][sub * 8 + j]) = make_float2(a[j], a[j+1]);
    if (sub == 0) { sM[id] = m; sL[id] = l; }
    __syncthreads();

    float M = sM[0];
    #pragma unroll
    for (int q = 1; q < 8; q++) M = fmaxf(M, sM[q]);
    float c[8];
    #pragma unroll
    for (int q = 0; q < 8; q++) c[q] = fexp2(sM[q] - M);
    float acc = 0.f, Lm = 0.f;
    #pragma unroll
    for (int q = 0; q < 8; q++) { acc = fmaf(c[q], sacc[q][t], acc); Lm = fmaf(c[q], sL[q], Lm); }
    float* o = part + ((size_t)b * NPART + p) * 260;
    o[t] = acc;
    if (t == 0) { o[256] = M; o[257] = Lm; }
}

// ---------------------------------------------------------------------------
// comb: per-batch merge of 16 partials -> wf[b][f] (normalized attention-
// weighted feature sum).
__global__ __launch_bounds__(256) void comb_kernel(const float* __restrict__ part,
                                                   float* __restrict__ wf)
{
    const int b = blockIdx.x, t = threadIdx.x;
    const float* pb = part + (size_t)b * NPART * 260;
    float M = -INFINITY;
    #pragma unroll
    for (int p = 0; p < NPART; p++) M = fmaxf(M, pb[p * 260 + 256]);
    float L = 0.f, acc = 0.f;
    #pragma unroll
    for (int p = 0; p < NPART; p++) {
        const float cc = fexp2(pb[p * 260 + 256] - M);
        L   = fmaf(cc, pb[p * 260 + 257], L);
        acc = fmaf(cc, pb[p * 260 + t], acc);
    }
    wf[b * 256 + t] = (t < 255) ? acc / L : 0.f;
}

// ---------------------------------------------------------------------------
// res: resT[h][b] = vb[h] + sum_f wf[b][f]*vW[h][f]. 128 blocks, each an
// 8-row h-slice for all 128 batches; wf chunked through LDS [f][b].
__global__ __launch_bounds__(512) void res_kernel(const float* __restrict__ vW,
                                                  const float* __restrict__ vb,
                                                  const float* __restrict__ wf,
                                                  float* __restrict__ resT)
{
    __shared__ float vws[8][256];    // 8 KB
    __shared__ float wfs[64][130];   // 33.3 KB (pad 130: read banks (2f+b)&31 -> free)
    const int g = blockIdx.x, t = threadIdx.x;
    #pragma unroll
    for (int i = 0; i < 4; i++) {
        const int idx = i * 512 + t, f = idx & 255, hh = idx >> 8;
        vws[hh][f] = (f < 255) ? vW[(g * 8 + hh) * 255 + f] : 0.f;
    }
    const int b = t & 127, ho = t >> 7;      // ho wave-uniform (w>>1)
    const int fl = t & 63, wv = t >> 6;
    float acc0 = 0.f, acc1 = 0.f;
    for (int c = 0; c < 4; c++) {
        __syncthreads();
        #pragma unroll
        for (int i = 0; i < 16; i++) {
            const int bb = i * 8 + wv;
            wfs[fl][bb] = wf[bb * 256 + c * 64 + fl];   // coalesced global read
        }
        __syncthreads();
        #pragma unroll 8
        for (int f = 0; f < 64; f++) {
            const float w2 = wfs[f][b];
            acc0 = fmaf(w2, vws[ho][c * 64 + f], acc0);
            acc1 = fmaf(w2, vws[ho + 4][c * 64 + f], acc1);
        }
    }
    const int h0 = g * 8 + ho, h1 = h0 + 4;
    resT[h0 * 128 + b] = acc0 + vb[h0];
    resT[h1 * 128 + b] = acc1 + vb[h1];
}

// ---------------------------------------------------------------------------
// h1: h1pre[b][j] += sum_{h in kchunk} resT[h][b]*W1[j][h].
// Grid (32 jblk, 2 bhalf, 4 kchunk); K-split partials via f32 atomicAdd.
__global__ __launch_bounds__(256) void h1_kernel(const float* __restrict__ W1,
                                                 const float* __restrict__ resT,
                                                 float* __restrict__ h1pre)
{
    __shared__ float W1s[16][256];   // 16 KB
    __shared__ float ress[64][66];   // 16.9 KB
    const int j0 = blockIdx.x * 16, b0 = blockIdx.y * 64, h0 = blockIdx.z * 256;
    const int t = threadIdx.x;
    #pragma unroll
    for (int i = 0; i < 16; i++) {
        const int idx = i * 256 + t, hl = idx & 255, jj = idx >> 8;
        W1s[jj][hl] = W1[(j0 + jj) * 1024 + h0 + hl];
    }
    const int bb = t & 63, jg = t >> 6;      // jg wave-uniform
    float acc[4] = {0.f, 0.f, 0.f, 0.f};
    for (int sc = 0; sc < 4; sc++) {
        __syncthreads();
        {
            const int bl = t & 63, wvv = t >> 6;
            #pragma unroll
            for (int i = 0; i < 16; i++) {
                const int hl = i * 4 + wvv;
                ress[hl][bl] = resT[(h0 + sc * 64 + hl) * 128 + b0 + bl];
            }
        }
        __syncthreads();
        #pragma unroll 4
        for (int hl = 0; hl < 64; hl++) {
            const float rv = ress[hl][bb];
            acc[0] = fmaf(rv, W1s[jg * 4 + 0][sc * 64 + hl], acc[0]);
            acc[1] = fmaf(rv, W1s[jg * 4 + 1][sc * 64 + hl], acc[1]);
            acc[2] = fmaf(rv, W1s[jg * 4 + 2][sc * 64 + hl], acc[2]);
            acc[3] = fmaf(rv, W1s[jg * 4 + 3][sc * 64 + hl], acc[3]);
        }
    }
    #pragma unroll
    for (int k = 0; k < 4; k++)
        atomicAdd(&h1pre[(size_t)(b0 + bb) * 512 + j0 + jg * 4 + k], acc[k]);
}

// ---------------------------------------------------------------------------
// h2out: h2[b][j2] = relu(b2[j2] + sum_j W2[j2][j]*relu(h1pre[b][j]+b1[j]));
// then partial out[b][o] += sum_{j2 in block} h2 * W3[o][j2] via atomicAdd
// (d_out zero-initialized by qk_kernel). Grid (32 j2blk, 2 bhalf).
__global__ __launch_bounds__(256) void h2out_kernel(const float* __restrict__ W2,
    const float* __restrict__ b1, const float* __restrict__ b2,
    const float* __restrict__ W3, const float* __restrict__ b3,
    const float* __restrict__ h1pre, float* __restrict__ out)
{
    __shared__ float W2s[8][512];    // 16 KB
    __shared__ float h1s[64][66];    // 16.9 KB
    __shared__ float po[4][64][2];   // 2 KB
    const int j20 = blockIdx.x * 8, b0 = blockIdx.y * 64;
    const int t = threadIdx.x;
    #pragma unroll
    for (int i = 0; i < 16; i++) {
        const int idx = i * 256 + t, jl = idx & 511, jj = idx >> 9;
        W2s[jj][jl] = W2[(j20 + jj) * 512 + jl];
    }
    const int bb = t & 63, jg = t >> 6;
    float acc[2] = {0.f, 0.f};
    for (int sc = 0; sc < 8; sc++) {
        __syncthreads();
        {
            const int jl = t & 63, wvv = t >> 6;
            #pragma unroll
            for (int i = 0; i < 16; i++) {
                const int bl = i * 4 + wvv;
                const float v = h1pre[(size_t)(b0 + bl) * 512 + sc * 64 + jl] + b1[sc * 64 + jl];
                h1s[jl][bl] = fmaxf(v, 0.f);   // relu applied on load
            }
        }
        __syncthreads();
        #pragma unroll 4
        for (int jl = 0; jl < 64; jl++) {
            const float hv = h1s[jl][bb];
            acc[0] = fmaf(hv, W2s[jg * 2 + 0][sc * 64 + jl], acc[0]);
            acc[1] = fmaf(hv, W2s[jg * 2 + 1][sc * 64 + jl], acc[1]);
        }
    }
    float p0 = 0.f, p1 = 0.f;
    #pragma unroll
    for (int k = 0; k < 2; k++) {
        const int j2 = j20 + jg * 2 + k;
        const float h2v = fmaxf(acc[k] + b2[j2], 0.f);
        p0 = fmaf(h2v, W3[j2],       p0);
        p1 = fmaf(h2v, W3[256 + j2], p1);
    }
    po[jg][bb][0] = p0;
    po[jg][bb][1] = p1;
    __syncthreads();
    if (t < 128) {
        const int b = t & 63, o = t >> 6;
        float s = po[0][b][o] + po[1][b][o] + po[2][b][o] + po[3][b][o];
        if (blockIdx.x == 0) s += b3[o];     // add bias exactly once per (b,o)
        atomicAdd(&out[(b0 + b) * 2 + o], s);
    }
}

// ---------------------------------------------------------------------------
extern "C" void kernel_launch(void* const* d_in, const int* in_sizes, int n_in,
                              void* d_out, int out_size, void* d_ws, size_t ws_size,
                              hipStream_t stream)
{
    (void)in_sizes; (void)n_in; (void)out_size; (void)ws_size;
    const float* in = (const float*)d_in[0];
    const float* kW = (const float*)d_in[1];
    // d_in[2] = kb: unused — q.kb is a per-batch constant score shift (softmax-invariant)
    const float* vW = (const float*)d_in[3];
    const float* vb = (const float*)d_in[4];
    const float* qW = (const float*)d_in[5];
    const float* qb = (const float*)d_in[6];
    const float* W1 = (const float*)d_in[7];
    const float* b1 = (const float*)d_in[8];
    const float* W2 = (const float*)d_in[9];
    const float* b2 = (const float*)d_in[10];
    const float* W3 = (const float*)d_in[11];
    const float* b3 = (const float*)d_in[12];

    char* ws = (char*)d_ws;
    float* kqp   = (float*)(ws + WS_KQP);
    float* part  = (float*)(ws + WS_PART);
    float* wf    = (float*)(ws + WS_WF);
    float* resT  = (float*)(ws + WS_REST);
    float* h1pre = (float*)(ws + WS_H1P);

    qk_kernel   <<<dim3(64, 4),         256, 0, stream>>>(in, kW, qW, qb, kqp, h1pre, (float*)d_out);
    attn_kernel <<<dim3(NPART, NBATCH), 256, 0, stream>>>(in, kqp, part);
    comb_kernel <<<128,                 256, 0, stream>>>(part, wf);
    res_kernel  <<<128,                 512, 0, stream>>>(vW, vb, wf, resT);
    h1_kernel   <<<dim3(32, 2, 4),      256, 0, stream>>>(W1, resT, h1pre);
    h2out_kernel<<<dim3(32, 2),         256, 0, stream>>>(W2, b1, b2, W3, b3, h1pre, (float*)d_out);
}

// Round 3
// 276.853 us; speedup vs baseline: 1.5011x; 1.1635x over previous
//
#include <hip/hip_runtime.h>
#include <stdint.h>

// B=128, S=1024, LAST=258, FEAT=255, HIDDEN=1024 — all f32 in/out.
#define NBATCH 128
#define SEQ    1024
#define ROWE   258
#define NPART  16

// ws layout (bytes), total ~3.41 MB
#define WS_KQP   0                       // float kqp[4][128][256]     512 KB
#define WS_PART  524288                  // float part[128][16][260]  2.03 MB
#define WS_WF    2654208                 // float wf[128][256]         128 KB
#define WS_REST  2785280                 // float resT[1024][128]      512 KB
#define WS_H1P   3309568                 // float h1pre[128][512]      256 KB

// NOTE (R1 post-mortem): fusing comb into attn via device-scope threadfence +
// atomic counter made attn 235 µs (was <79): on gfx950 __threadfence is an L2
// writeback/invalidate (per-XCD L2s non-coherent) — 2048 release fences
// serialized at L2 and evicted the streamed input. Never cross-block-fuse with
// fences here; the inter-kernel barrier is far cheaper.
// NOTE (R2 post-mortem): __launch_bounds__(256,8) on attn forced VGPR=32 and
// spilled the k/x/xn/a register arrays -> WRITE_SIZE 140 MB of scratch, 105 µs.
// Spill signature: tiny VGPR_Count + WRITE_SIZE >> legitimate output bytes.

static __device__ __forceinline__ float fexp2(float x){ return __builtin_amdgcn_exp2f(x); }

// ---------------------------------------------------------------------------
// qk: grid (64 batch-pairs, 4 h-quarters). kqp[hh][b][f] = partial over h-quarter
//     of (qb[h] + sum_j archi[b][j] qW[h][j]) * kW[h][f]. Unscaled; attn sums the
//     4 partials and applies log2(e)/sqrt(258). Also zero-inits h1pre and d_out
//     (consumed via atomicAdd later). q.kb dropped: softmax-invariant shift.
__global__ __launch_bounds__(256) void qk_kernel(const float* __restrict__ in,
    const float* __restrict__ kW, const float* __restrict__ qW,
    const float* __restrict__ qb, float* __restrict__ kqp,
    float* __restrict__ h1pre, float* __restrict__ out)
{
    __shared__ float qv[2][256];
    const int bb = blockIdx.x;         // 0..63
    const int hh = blockIdx.y;         // 0..3
    const int t  = threadIdx.x;
    const int b0 = bb * 2;
    if (hh == 0) {
        h1pre[(size_t)b0 * 512 + t]             = 0.f;
        h1pre[(size_t)b0 * 512 + 256 + t]       = 0.f;
        h1pre[(size_t)(b0 + 1) * 512 + t]       = 0.f;
        h1pre[(size_t)(b0 + 1) * 512 + 256 + t] = 0.f;
        if (t < 4) out[b0 * 2 + t] = 0.f;
    }
    const int h = hh * 256 + t;
    const float w0 = qW[h * 3 + 0], w1 = qW[h * 3 + 1], w2 = qW[h * 3 + 2], bq = qb[h];
    #pragma unroll
    for (int u = 0; u < 2; u++) {
        const size_t abase = (size_t)(b0 + u) * (SEQ * ROWE) + 255; // input[b,0,255..257]
        qv[u][t] = bq + in[abase] * w0 + in[abase + 1] * w1 + in[abase + 2] * w2;
    }
    __syncthreads();
    const int col = (t < 255) ? t : 254;            // t==255 is a pad slot
    const float* kWp = kW + (size_t)(hh * 256) * 255 + col;
    float acc0 = 0.f, acc1 = 0.f;
    #pragma unroll 16
    for (int i = 0; i < 256; i++) {
        const float kv = kWp[(size_t)i * 255];      // coalesced across t
        acc0 = fmaf(qv[0][i], kv, acc0);            // LDS broadcast reads
        acc1 = fmaf(qv[1][i], kv, acc1);
    }
    kqp[(size_t)((hh << 7) + b0) * 256 + t]       = (t < 255) ? acc0 : 0.f;
    kqp[(size_t)((hh << 7) + b0 + 1) * 256 + t]   = (t < 255) ? acc1 : 0.f;
}

// ---------------------------------------------------------------------------
// attn: grid (16,128) — (S-chunk of 64 rows, batch). Geometry: 32 lanes per
// row, 2 rows per wave concurrently (lane half hf owns row p*64+w*16+2i+hf,
// 8 floats per lane). Butterfly is 5 steps over 32 lanes, 8 iters/wave
// (40 shuffles vs 96 in the 64-lane/row version); softmax-update serial issues
// halved; per-wave reads are 2 adjacent rows (contiguous 2 KB span). 8 online
// states (4 waves × 2 halves) merged through LDS at the end.
// __launch_bounds__(256,4): VGPR cap 128 — the (256,8)=64-cap spilled (R2).
__global__ __launch_bounds__(256, 4) void attn_kernel(const float* __restrict__ in,
                                                      const float* __restrict__ kqp,
                                                      float* __restrict__ part)
{
    __shared__ float sM[8], sL[8], sacc[8][256];
    const int p = blockIdx.x, b = blockIdx.y;
    const int t = threadIdx.x, w = t >> 6, lane = t & 63;
    const int hf = lane >> 5, sub = lane & 31;   // half (row parity), sub-lane

    const float SCALE = (float)(1.4426950408889634 / 16.062378404209142); // log2(e)/sqrt(258)
    // k registers: lane covers features f = sub*8 + j. kqp rows 1 KB-aligned ->
    // sub*32 B offsets are 16 B-aligned: float4 loads OK. f=255 slot is 0 (qk pad).
    float k[8];
    {
        float s0x=0.f,s0y=0.f,s0z=0.f,s0w=0.f, s1x=0.f,s1y=0.f,s1z=0.f,s1w=0.f;
        #pragma unroll
        for (int hh = 0; hh < 4; hh++) {
            const float4* pp = (const float4*)(kqp + (size_t)((hh << 7) + b) * 256 + sub * 8);
            const float4 u = pp[0], v = pp[1];
            s0x+=u.x; s0y+=u.y; s0z+=u.z; s0w+=u.w;
            s1x+=v.x; s1y+=v.y; s1z+=v.z; s1w+=v.w;
        }
        k[0]=s0x*SCALE; k[1]=s0y*SCALE; k[2]=s0z*SCALE; k[3]=s0w*SCALE;
        k[4]=s1x*SCALE; k[5]=s1y*SCALE; k[6]=s1z*SCALE; k[7]=s1w*SCALE;
    }

    // rows r = p*64 + w*16 + 2*i + hf, i=0..7. Row byte base = r*1032 (8-aligned);
    // per-lane 8 floats at +sub*32 B -> float2 loads aligned.
    const float* rp = in + ((size_t)b * SEQ + p * 64 + w * 16 + hf) * ROWE + sub * 8;

    float x[8], xn[8], a[8];
    #pragma unroll
    for (int j = 0; j < 8; j++) a[j] = 0.f;
    #pragma unroll
    for (int j = 0; j < 8; j += 2) {
        const float2 v2 = *(const float2*)(rp + j);
        x[j] = v2.x; x[j+1] = v2.y;
    }
    rp += 2 * ROWE;
    float m = -INFINITY, l = 0.f;

    #pragma unroll
    for (int i = 0; i < 8; i++) {
        if (i < 7) {                       // prefetch next row pair
            #pragma unroll
            for (int j = 0; j < 8; j += 2) {
                const float2 v2 = *(const float2*)(rp + j);
                xn[j] = v2.x; xn[j+1] = v2.y;
            }
            rp += 2 * ROWE;
        }
        // tree dot: shorter dependent chain than a linear fma chain
        const float d0 = fmaf(x[0], k[0], x[1] * k[1]);
        const float d1 = fmaf(x[2], k[2], x[3] * k[3]);
        const float d2 = fmaf(x[4], k[4], x[5] * k[5]);
        const float d3 = fmaf(x[6], k[6], x[7] * k[7]);
        float d = (d0 + d1) + (d2 + d3);
        #pragma unroll
        for (int off = 16; off > 0; off >>= 1) d += __shfl_xor(d, off, 64); // stays in half
        const float mn = fmaxf(m, d);
        const float cc = fexp2(m - mn);    // first iter: exp2(-inf)=0
        const float wt = fexp2(d - mn);
        l = fmaf(l, cc, wt);
        #pragma unroll
        for (int j = 0; j < 8; j++) a[j] = fmaf(a[j], cc, wt * x[j]);
        m = mn;
        if (i < 7) {
            #pragma unroll
            for (int j = 0; j < 8; j++) x[j] = xn[j];   // register rename, free
        }
    }

    const int id = w * 2 + hf;             // 8 partial states per block
    #pragma unroll
    for (int j = 0; j < 8; j += 2)
        *(float2*)(&sacc[id][sub * 8 + j]) = make_float2(a[j], a[j+1]);
    if (sub == 0) { sM[id] = m; sL[id] = l; }
    __syncthreads();

    float M = sM[0];
    #pragma unroll
    for (int q = 1; q < 8; q++) M = fmaxf(M, sM[q]);
    float c[8];
    #pragma unroll
    for (int q = 0; q < 8; q++) c[q] = fexp2(sM[q] - M);
    float acc = 0.f, Lm = 0.f;
    #pragma unroll
    for (int q = 0; q < 8; q++) { acc = fmaf(c[q], sacc[q][t], acc); Lm = fmaf(c[q], sL[q], Lm); }
    float* o = part + ((size_t)b * NPART + p) * 260;
    o[t] = acc;
    if (t == 0) { o[256] = M; o[257] = Lm; }
}

// ---------------------------------------------------------------------------
// comb: per-batch merge of 16 partials -> wf[b][f] (normalized attention-
// weighted feature sum).
__global__ __launch_bounds__(256) void comb_kernel(const float* __restrict__ part,
                                                   float* __restrict__ wf)
{
    const int b = blockIdx.x, t = threadIdx.x;
    const float* pb = part + (size_t)b * NPART * 260;
    float M = -INFINITY;
    #pragma unroll
    for (int p = 0; p < NPART; p++) M = fmaxf(M, pb[p * 260 + 256]);
    float L = 0.f, acc = 0.f;
    #pragma unroll
    for (int p = 0; p < NPART; p++) {
        const float cc = fexp2(pb[p * 260 + 256] - M);
        L   = fmaf(cc, pb[p * 260 + 257], L);
        acc = fmaf(cc, pb[p * 260 + t], acc);
    }
    wf[b * 256 + t] = (t < 255) ? acc / L : 0.f;
}

// ---------------------------------------------------------------------------
// res: resT[h][b] = vb[h] + sum_f wf[b][f]*vW[h][f]. 128 blocks, each an
// 8-row h-slice for all 128 batches; wf chunked through LDS [f][b].
__global__ __launch_bounds__(512) void res_kernel(const float* __restrict__ vW,
                                                  const float* __restrict__ vb,
                                                  const float* __restrict__ wf,
                                                  float* __restrict__ resT)
{
    __shared__ float vws[8][256];    // 8 KB
    __shared__ float wfs[64][130];   // 33.3 KB (pad 130: read banks (2f+b)&31 -> free)
    const int g = blockIdx.x, t = threadIdx.x;
    #pragma unroll
    for (int i = 0; i < 4; i++) {
        const int idx = i * 512 + t, f = idx & 255, hh = idx >> 8;
        vws[hh][f] = (f < 255) ? vW[(g * 8 + hh) * 255 + f] : 0.f;
    }
    const int b = t & 127, ho = t >> 7;      // ho wave-uniform (w>>1)
    const int fl = t & 63, wv = t >> 6;
    float acc0 = 0.f, acc1 = 0.f;
    for (int c = 0; c < 4; c++) {
        __syncthreads();
        #pragma unroll
        for (int i = 0; i < 16; i++) {
            const int bb = i * 8 + wv;
            wfs[fl][bb] = wf[bb * 256 + c * 64 + fl];   // coalesced global read
        }
        __syncthreads();
        #pragma unroll 8
        for (int f = 0; f < 64; f++) {
            const float w2 = wfs[f][b];
            acc0 = fmaf(w2, vws[ho][c * 64 + f], acc0);
            acc1 = fmaf(w2, vws[ho + 4][c * 64 + f], acc1);
        }
    }
    const int h0 = g * 8 + ho, h1 = h0 + 4;
    resT[h0 * 128 + b] = acc0 + vb[h0];
    resT[h1 * 128 + b] = acc1 + vb[h1];
}

// ---------------------------------------------------------------------------
// h1: h1pre[b][j] += sum_{h in kchunk} resT[h][b]*W1[j][h].
// Grid (32 jblk, 2 bhalf, 4 kchunk); K-split partials via f32 atomicAdd.
__global__ __launch_bounds__(256) void h1_kernel(const float* __restrict__ W1,
                                                 const float* __restrict__ resT,
                                                 float* __restrict__ h1pre)
{
    __shared__ float W1s[16][256];   // 16 KB
    __shared__ float ress[64][66];   // 16.9 KB
    const int j0 = blockIdx.x * 16, b0 = blockIdx.y * 64, h0 = blockIdx.z * 256;
    const int t = threadIdx.x;
    #pragma unroll
    for (int i = 0; i < 16; i++) {
        const int idx = i * 256 + t, hl = idx & 255, jj = idx >> 8;
        W1s[jj][hl] = W1[(j0 + jj) * 1024 + h0 + hl];
    }
    const int bb = t & 63, jg = t >> 6;      // jg wave-uniform
    float acc[4] = {0.f, 0.f, 0.f, 0.f};
    for (int sc = 0; sc < 4; sc++) {
        __syncthreads();
        {
            const int bl = t & 63, wvv = t >> 6;
            #pragma unroll
            for (int i = 0; i < 16; i++) {
                const int hl = i * 4 + wvv;
                ress[hl][bl] = resT[(h0 + sc * 64 + hl) * 128 + b0 + bl];
            }
        }
        __syncthreads();
        #pragma unroll 4
        for (int hl = 0; hl < 64; hl++) {
            const float rv = ress[hl][bb];
            acc[0] = fmaf(rv, W1s[jg * 4 + 0][sc * 64 + hl], acc[0]);
            acc[1] = fmaf(rv, W1s[jg * 4 + 1][sc * 64 + hl], acc[1]);
            acc[2] = fmaf(rv, W1s[jg * 4 + 2][sc * 64 + hl], acc[2]);
            acc[3] = fmaf(rv, W1s[jg * 4 + 3][sc * 64 + hl], acc[3]);
        }
    }
    #pragma unroll
    for (int k = 0; k < 4; k++)
        atomicAdd(&h1pre[(size_t)(b0 + bb) * 512 + j0 + jg * 4 + k], acc[k]);
}

// ---------------------------------------------------------------------------
// h2out: h2[b][j2] = relu(b2[j2] + sum_j W2[j2][j]*relu(h1pre[b][j]+b1[j]));
// then partial out[b][o] += sum_{j2 in block} h2 * W3[o][j2] via atomicAdd
// (d_out zero-initialized by qk_kernel). Grid (32 j2blk, 2 bhalf).
__global__ __launch_bounds__(256) void h2out_kernel(const float* __restrict__ W2,
    const float* __restrict__ b1, const float* __restrict__ b2,
    const float* __restrict__ W3, const float* __restrict__ b3,
    const float* __restrict__ h1pre, float* __restrict__ out)
{
    __shared__ float W2s[8][512];    // 16 KB
    __shared__ float h1s[64][66];    // 16.9 KB
    __shared__ float po[4][64][2];   // 2 KB
    const int j20 = blockIdx.x * 8, b0 = blockIdx.y * 64;
    const int t = threadIdx.x;
    #pragma unroll
    for (int i = 0; i < 16; i++) {
        const int idx = i * 256 + t, jl = idx & 511, jj = idx >> 9;
        W2s[jj][jl] = W2[(j20 + jj) * 512 + jl];
    }
    const int bb = t & 63, jg = t >> 6;
    float acc[2] = {0.f, 0.f};
    for (int sc = 0; sc < 8; sc++) {
        __syncthreads();
        {
            const int jl = t & 63, wvv = t >> 6;
            #pragma unroll
            for (int i = 0; i < 16; i++) {
                const int bl = i * 4 + wvv;
                const float v = h1pre[(size_t)(b0 + bl) * 512 + sc * 64 + jl] + b1[sc * 64 + jl];
                h1s[jl][bl] = fmaxf(v, 0.f);   // relu applied on load
            }
        }
        __syncthreads();
        #pragma unroll 4
        for (int jl = 0; jl < 64; jl++) {
            const float hv = h1s[jl][bb];
            acc[0] = fmaf(hv, W2s[jg * 2 + 0][sc * 64 + jl], acc[0]);
            acc[1] = fmaf(hv, W2s[jg * 2 + 1][sc * 64 + jl], acc[1]);
        }
    }
    float p0 = 0.f, p1 = 0.f;
    #pragma unroll
    for (int k = 0; k < 2; k++) {
        const int j2 = j20 + jg * 2 + k;
        const float h2v = fmaxf(acc[k] + b2[j2], 0.f);
        p0 = fmaf(h2v, W3[j2],       p0);
        p1 = fmaf(h2v, W3[256 + j2], p1);
    }
    po[jg][bb][0] = p0;
    po[jg][bb][1] = p1;
    __syncthreads();
    if (t < 128) {
        const int b = t & 63, o = t >> 6;
        float s = po[0][b][o] + po[1][b][o] + po[2][b][o] + po[3][b][o];
        if (blockIdx.x == 0) s += b3[o];     // add bias exactly once per (b,o)
        atomicAdd(&out[(b0 + b) * 2 + o], s);
    }
}

// ---------------------------------------------------------------------------
extern "C" void kernel_launch(void* const* d_in, const int* in_sizes, int n_in,
                              void* d_out, int out_size, void* d_ws, size_t ws_size,
                              hipStream_t stream)
{
    (void)in_sizes; (void)n_in; (void)out_size; (void)ws_size;
    const float* in = (const float*)d_in[0];
    const float* kW = (const float*)d_in[1];
    // d_in[2] = kb: unused — q.kb is a per-batch constant score shift (softmax-invariant)
    const float* vW = (const float*)d_in[3];
    const float* vb = (const float*)d_in[4];
    const float* qW = (const float*)d_in[5];
    const float* qb = (const float*)d_in[6];
    const float* W1 = (const float*)d_in[7];
    const float* b1 = (const float*)d_in[8];
    const float* W2 = (const float*)d_in[9];
    const float* b2 = (const float*)d_in[10];
    const float* W3 = (const float*)d_in[11];
    const float* b3 = (const float*)d_in[12];

    char* ws = (char*)d_ws;
    float* kqp   = (float*)(ws + WS_KQP);
    float* part  = (float*)(ws + WS_PART);
    float* wf    = (float*)(ws + WS_WF);
    float* resT  = (float*)(ws + WS_REST);
    float* h1pre = (float*)(ws + WS_H1P);

    qk_kernel   <<<dim3(64, 4),         256, 0, stream>>>(in, kW, qW, qb, kqp, h1pre, (float*)d_out);
    attn_kernel <<<dim3(NPART, NBATCH), 256, 0, stream>>>(in, kqp, part);
    comb_kernel <<<128,                 256, 0, stream>>>(part, wf);
    res_kernel  <<<128,                 512, 0, stream>>>(vW, vb, wf, resT);
    h1_kernel   <<<dim3(32, 2, 4),      256, 0, stream>>>(W1, resT, h1pre);
    h2out_kernel<<<dim3(32, 2),         256, 0, stream>>>(W2, b1, b2, W3, b3, h1pre, (float*)d_out);
}